// Round 9
// baseline (213.929 us; speedup 1.0000x reference)
//
#include <hip/hip_runtime.h>
#include <hip/hip_fp16.h>

#define N_NODES 50000
#define E_EDGES 800000
#define SCAN_TILE 1024
#define SCAN_NBLK ((N_NODES + SCAN_TILE - 1) / SCAN_TILE)   // 49
#define EW_EPT 4    // edges per octet per wave-iteration in edge_weights

__device__ __forceinline__ float sgpr_f(float x) {
    return __uint_as_float(__builtin_amdgcn_readfirstlane(__float_as_uint(x)));
}

#if defined(__has_builtin)
#if __has_builtin(__builtin_amdgcn_fdot2)
#define HAS_FDOT2 1
#endif
#endif

typedef _Float16 v2h_t __attribute__((ext_vector_type(2)));

__device__ __forceinline__ float fdot2f(__half2 a, __half2 b, float c) {
#ifdef HAS_FDOT2
    return __builtin_amdgcn_fdot2(*reinterpret_cast<v2h_t*>(&a),
                                  *reinterpret_cast<v2h_t*>(&b), c, false);
#else
    const float2 fa = __half22float2(a);
    const float2 fb = __half22float2(b);
    return fmaf(fa.x, fb.x, fmaf(fa.y, fb.y, c));
#endif
}

// packed relu: v_pk_max_f16 with inline constant 0 (no __hmax2 in ROCm 7.2 headers)
__device__ __forceinline__ __half2 relu_h2(__half2 x) {
    union { __half2 h; unsigned u; } a, r;
    a.h = x;
    asm("v_pk_max_f16 %0, %1, 0" : "=v"(r.u) : "v"(a.u));
    return r.h;
}

// ---------------------------------------------------------------------------
// Projection kernel: xq = q@Wq+bq, xk = k@Wk+bk, xv = v@Wv+bv  (N x 64 each)
// Outputs stored as fp16 to halve downstream gather traffic.
// ---------------------------------------------------------------------------
__global__ __launch_bounds__(256) void proj_kernel(
    const float* __restrict__ qin, const float* __restrict__ kin, const float* __restrict__ vin,
    const float* __restrict__ Wq, const float* __restrict__ bq,
    const float* __restrict__ Wk, const float* __restrict__ bk,
    const float* __restrict__ Wv, const float* __restrict__ bv,
    __half* __restrict__ xq, __half* __restrict__ xk, __half* __restrict__ xv)
{
    __shared__ float Ws[3 * 4096];
    const int tid = threadIdx.x;
    #pragma unroll
    for (int it = 0; it < 16; ++it) {
        const int idx = it * 256 + tid;
        Ws[idx]        = Wq[idx];
        Ws[4096 + idx] = Wk[idx];
        Ws[8192 + idx] = Wv[idx];
    }
    __syncthreads();

    const int cg = tid & 15;
    const int rg = tid >> 4;
    const int c0 = cg * 4;
    const int base = blockIdx.x * 64 + rg * 4;

    const float* ins[3]  = {qin, kin, vin};
    const float* bs[3]   = {bq, bk, bv};
    __half*      outs[3] = {xq, xk, xv};

    int rowi[4];
    #pragma unroll
    for (int rr = 0; rr < 4; ++rr)
        rowi[rr] = (base + rr < N_NODES) ? (base + rr) : (N_NODES - 1);

    #pragma unroll
    for (int m = 0; m < 3; ++m) {
        const float* in = ins[m];
        const float* Wm = &Ws[m * 4096];
        float4 acc[4];
        const float4 b4 = *reinterpret_cast<const float4*>(&bs[m][c0]);
        #pragma unroll
        for (int rr = 0; rr < 4; ++rr) acc[rr] = b4;

        for (int kk = 0; kk < 64; kk += 4) {
            float4 rv[4];
            #pragma unroll
            for (int rr = 0; rr < 4; ++rr)
                rv[rr] = *reinterpret_cast<const float4*>(&in[rowi[rr] * 64 + kk]);
            #pragma unroll
            for (int dk = 0; dk < 4; ++dk) {
                const float4 w4 = *reinterpret_cast<const float4*>(&Wm[(kk + dk) * 64 + c0]);
                #pragma unroll
                for (int rr = 0; rr < 4; ++rr) {
                    const float xs = reinterpret_cast<const float*>(&rv[rr])[dk];
                    acc[rr].x = fmaf(xs, w4.x, acc[rr].x);
                    acc[rr].y = fmaf(xs, w4.y, acc[rr].y);
                    acc[rr].z = fmaf(xs, w4.z, acc[rr].z);
                    acc[rr].w = fmaf(xs, w4.w, acc[rr].w);
                }
            }
        }
        #pragma unroll
        for (int rr = 0; rr < 4; ++rr) {
            if (base + rr < N_NODES) {
                union { __half2 h[2]; uint2 u; } pk;
                pk.h[0] = __floats2half2_rn(acc[rr].x, acc[rr].y);
                pk.h[1] = __floats2half2_rn(acc[rr].z, acc[rr].w);
                *reinterpret_cast<uint2*>(&outs[m][(size_t)(base + rr) * 64 + c0]) = pk.u;
            }
        }
    }
}

// ---------------------------------------------------------------------------
// Hierarchical scan, step A: per-1024-element block sums (49 blocks).
// ---------------------------------------------------------------------------
__global__ __launch_bounds__(256) void scan_sums(
    const int* __restrict__ cnt, int* __restrict__ bsum)
{
    const int tid  = threadIdx.x;
    const int base = blockIdx.x * SCAN_TILE + tid * 4;
    int s = 0;
    if (base + 3 < N_NODES) {
        const int4 t = *reinterpret_cast<const int4*>(&cnt[base]);
        s = t.x + t.y + t.z + t.w;
    } else {
        #pragma unroll
        for (int i = 0; i < 4; ++i)
            if (base + i < N_NODES) s += cnt[base + i];
    }
    #pragma unroll
    for (int d = 1; d < 64; d <<= 1) s += __shfl_xor(s, d);
    __shared__ int ws[4];
    if ((tid & 63) == 0) ws[tid >> 6] = s;
    __syncthreads();
    if (tid == 0) bsum[blockIdx.x] = ws[0] + ws[1] + ws[2] + ws[3];
}

// ---------------------------------------------------------------------------
// Hierarchical scan, step B: exclusive scan of the 49 block sums (one wave).
// ---------------------------------------------------------------------------
__global__ __launch_bounds__(64) void scan_bsum(int* __restrict__ bsum)
{
    const int lane = threadIdx.x;
    const int v = (lane < SCAN_NBLK) ? bsum[lane] : 0;
    int incl = v;
    #pragma unroll
    for (int d = 1; d < 64; d <<= 1) {
        const int t = __shfl_up(incl, d);
        if (lane >= d) incl += t;
    }
    if (lane < SCAN_NBLK) bsum[lane] = incl - v;
}

// ---------------------------------------------------------------------------
// Hierarchical scan, step C: local exclusive scan + block offset.
// Writes off[] and re-purposes cnt[] (in-place) as the scatter cursor.
// ---------------------------------------------------------------------------
__global__ __launch_bounds__(256) void scan_final(
    int* __restrict__ cnt, const int* __restrict__ bsum, int* __restrict__ off)
{
    const int tid  = threadIdx.x;
    const int base = blockIdx.x * SCAN_TILE + tid * 4;

    int v0 = 0, v1 = 0, v2 = 0, v3 = 0;
    if (base + 3 < N_NODES) {
        const int4 t = *reinterpret_cast<const int4*>(&cnt[base]);
        v0 = t.x; v1 = t.y; v2 = t.z; v3 = t.w;
    } else {
        if (base + 0 < N_NODES) v0 = cnt[base + 0];
        if (base + 1 < N_NODES) v1 = cnt[base + 1];
        if (base + 2 < N_NODES) v2 = cnt[base + 2];
        if (base + 3 < N_NODES) v3 = cnt[base + 3];
    }
    const int s = v0 + v1 + v2 + v3;

    int incl = s;
    #pragma unroll
    for (int d = 1; d < 64; d <<= 1) {
        const int t = __shfl_up(incl, d);
        if ((tid & 63) >= d) incl += t;
    }
    __shared__ int wsum[4];
    const int wave = tid >> 6;
    if ((tid & 63) == 63) wsum[wave] = incl;
    __syncthreads();
    int woff = 0;
    #pragma unroll
    for (int w = 0; w < 3; ++w)
        if (w < wave) woff += wsum[w];

    int run = bsum[blockIdx.x] + woff + (incl - s);
    if (base + 0 < N_NODES) { off[base + 0] = run; cnt[base + 0] = run; run += v0; }
    if (base + 1 < N_NODES) { off[base + 1] = run; cnt[base + 1] = run; run += v1; }
    if (base + 2 < N_NODES) { off[base + 2] = run; cnt[base + 2] = run; run += v2; }
    if (base + 3 < N_NODES) { off[base + 3] = run; cnt[base + 3] = run; run += v3; }

    if (blockIdx.x == 0 && tid == 0) off[N_NODES] = E_EDGES;
}

// ---------------------------------------------------------------------------
// Edge-weights kernel, COALESCED edge-order outputs. Octet (8 lanes) per edge.
// Lane r: channels 8r..8r+7 (one dwordx4 fp16 load per node row). W1
// contraction via packed v_dot2_f32_f16. Writes wout[e] (16B, coalesced),
// ep2e[e]={p,dst} (8B, coalesced), and the degree histogram atomic.
// ---------------------------------------------------------------------------
__global__ __launch_bounds__(256) void edge_weights(
    const int* __restrict__ eidx, const float* __restrict__ edges,
    const float* __restrict__ Wp, const float* __restrict__ bp,
    const float* __restrict__ W1, const float* __restrict__ b1,
    const float* __restrict__ W2, const float* __restrict__ b2,
    const __half* __restrict__ xq, const __half* __restrict__ xk,
    int* __restrict__ cnt, float2* __restrict__ ep2e, ushort* __restrict__ wout16)
{
    const int tid  = threadIdx.x;
    const int lane = tid & 63;
    const int o    = lane >> 3;
    const int r    = lane & 7;
    const int wave = tid >> 6;

    // W1 slice rows 8r..8r+7 packed as half2 over row pairs:
    // W1h[i][jj] = { W1[(8r+2i)*8+jj], W1[(8r+2i+1)*8+jj] }
    __half2 W1h[4][8];
    #pragma unroll
    for (int i = 0; i < 4; ++i) {
        const float4 a0 = *reinterpret_cast<const float4*>(&W1[(8 * r + 2 * i) * 8]);
        const float4 a1 = *reinterpret_cast<const float4*>(&W1[(8 * r + 2 * i) * 8 + 4]);
        const float4 c0 = *reinterpret_cast<const float4*>(&W1[(8 * r + 2 * i + 1) * 8]);
        const float4 c1 = *reinterpret_cast<const float4*>(&W1[(8 * r + 2 * i + 1) * 8 + 4]);
        W1h[i][0] = __floats2half2_rn(a0.x, c0.x);
        W1h[i][1] = __floats2half2_rn(a0.y, c0.y);
        W1h[i][2] = __floats2half2_rn(a0.z, c0.z);
        W1h[i][3] = __floats2half2_rn(a0.w, c0.w);
        W1h[i][4] = __floats2half2_rn(a1.x, c1.x);
        W1h[i][5] = __floats2half2_rn(a1.y, c1.y);
        W1h[i][6] = __floats2half2_rn(a1.z, c1.z);
        W1h[i][7] = __floats2half2_rn(a1.w, c1.w);
    }
    // W2 column r (per-lane, distributed logit)
    float W2col[8];
    #pragma unroll
    for (int jj = 0; jj < 8; ++jj) W2col[jj] = W2[jj * 8 + r];
    // uniform biases -> SGPRs
    float b1u[8];
    #pragma unroll
    for (int j = 0; j < 8; ++j) b1u[j] = sgpr_f(b1[j]);
    const float b2r = b2[r];
    const float wpA = Wp[2 * r], wpB = Wp[2 * r + 1];
    const float bp0 = sgpr_f(bp[0]);

    const int wb = (blockIdx.x * 4 + wave) * (8 * EW_EPT);

    #pragma unroll
    for (int t = 0; t < EW_EPT; ++t) {
        const int e = wb + t * 8 + o;

        const int2 sd = *reinterpret_cast<const int2*>(&eidx[2 * e]);
        const float2 e2 = *reinterpret_cast<const float2*>(&edges[(size_t)e * 16 + 2 * r]);

        uint4 q4u = *reinterpret_cast<const uint4*>(&xq[(size_t)sd.x * 64 + 8 * r]);
        uint4 k4u = *reinterpret_cast<const uint4*>(&xk[(size_t)sd.y * 64 + 8 * r]);

        // p = edges[e].Wp + bp (16-dot over the octet)
        float p = fmaf(e2.x, wpA, e2.y * wpB);
        p += __shfl_xor(p, 1);
        p += __shfl_xor(p, 2);
        p += __shfl_xor(p, 4);
        p += bp0;

        // relu(xk - xq + p) in packed half2, then dot2 into f32 partials
        const __half2 p2 = __float2half2_rn(p);
        const __half2* qh = reinterpret_cast<const __half2*>(&q4u);
        const __half2* kh = reinterpret_cast<const __half2*>(&k4u);

        float part[8];
        #pragma unroll
        for (int jj = 0; jj < 8; ++jj) part[jj] = 0.f;
        #pragma unroll
        for (int i = 0; i < 4; ++i) {
            const __half2 d = relu_h2(__hadd2(__hsub2(kh[i], qh[i]), p2));
            #pragma unroll
            for (int jj = 0; jj < 8; ++jj)
                part[jj] = fdot2f(d, W1h[i][jj], part[jj]);
        }
        // octet butterfly: every lane gets the full h1 vector
        #pragma unroll
        for (int jj = 0; jj < 8; ++jj) {
            part[jj] += __shfl_xor(part[jj], 1);
            part[jj] += __shfl_xor(part[jj], 2);
            part[jj] += __shfl_xor(part[jj], 4);
        }

        // distributed logit: lane r computes h2[r] only
        float h2 = b2r;
        #pragma unroll
        for (int jj = 0; jj < 8; ++jj) {
            const float h1 = fmaxf(part[jj] + b1u[jj], 0.f);
            h2 = fmaf(h1, W2col[jj], h2);
        }

        // octet softmax
        float mx = h2;
        mx = fmaxf(mx, __shfl_xor(mx, 1));
        mx = fmaxf(mx, __shfl_xor(mx, 2));
        mx = fmaxf(mx, __shfl_xor(mx, 4));
        const float ex = __expf(h2 - mx);
        float s = ex;
        s += __shfl_xor(s, 1);
        s += __shfl_xor(s, 2);
        s += __shfl_xor(s, 4);
        const float w = ex / s;

        // coalesced edge-order outputs
        wout16[(size_t)e * 8 + r] = __half_as_ushort(__float2half_rn(w));
        if (r == 0) ep2e[e] = make_float2(p, __int_as_float(sd.y));
        if (r == 1) atomicAdd(&cnt[sd.x], 1);
    }
}

// ---------------------------------------------------------------------------
// Permutation scatter: only 4B per edge goes to a random CSR slot.
// ---------------------------------------------------------------------------
__global__ __launch_bounds__(256) void perm_scatter(
    const int* __restrict__ eidx, int* __restrict__ cursor, int* __restrict__ perm)
{
    const int e = blockIdx.x * 256 + threadIdx.x;
    const int src = eidx[2 * e];
    const int pos = atomicAdd(&cursor[src], 1);
    perm[pos] = e;
}

// ---------------------------------------------------------------------------
// Node accumulation: 16 lanes per node (2 sub-octets split the edge list,
// stride 2). Lane r owns channels 8r..8r+7. Per edge: perm[j] -> edge id,
// then gather ep2e[e], wout[e] (wave-broadcast, L2/L3-resident) and xv row.
// ---------------------------------------------------------------------------
__global__ __launch_bounds__(256) void node_accum(
    const int* __restrict__ off, const int* __restrict__ perm,
    const float2* __restrict__ ep2e, const uint4* __restrict__ woute,
    const __half* __restrict__ xv, float* __restrict__ out)
{
    const int tid  = threadIdx.x;
    const int lane = tid & 63;
    const int grp  = lane >> 4;        // 4 node-groups per wave
    const int sub  = (lane >> 3) & 1;  // sub-octet within group
    const int r    = lane & 7;         // channel block
    const int wave = tid >> 6;

    const int node = blockIdx.x * 16 + wave * 4 + grp;   // always < 50000

    const int beg = off[node];
    const int end = off[node + 1];

    float acc[8];
    #pragma unroll
    for (int i = 0; i < 8; ++i) acc[i] = 0.f;

    int j = beg + sub;
    float2 ep;
    uint4  w8;
    if (j < end) {
        const int e = perm[j];
        ep = ep2e[e];
        w8 = woute[e];
    }

    for (; j < end; j += 2) {
        const float p   = ep.x;
        const int   dst = __float_as_int(ep.y);

        union { uint4 u; __half2 h[4]; } v4, wz;
        v4.u = *reinterpret_cast<const uint4*>(&xv[(size_t)dst * 64 + 8 * r]);
        wz.u = w8;

        // prefetch next record through the perm indirection
        if (j + 2 < end) {
            const int e2 = perm[j + 2];
            ep = ep2e[e2];
            w8 = woute[e2];
        }

        #pragma unroll
        for (int i = 0; i < 4; ++i) {
            const float2 fv = __half22float2(v4.h[i]);
            const float2 fw = __half22float2(wz.h[i]);
            acc[2 * i]     = fmaf(fv.x + p, fw.x, acc[2 * i]);
            acc[2 * i + 1] = fmaf(fv.y + p, fw.y, acc[2 * i + 1]);
        }
    }

    // merge the two sub-octets
    #pragma unroll
    for (int i = 0; i < 8; ++i)
        acc[i] += __shfl_xor(acc[i], 8);

    if (sub == 0) {
        float* orow = &out[(size_t)node * 64 + 8 * r];
        *reinterpret_cast<float4*>(orow)     = make_float4(acc[0], acc[1], acc[2], acc[3]);
        *reinterpret_cast<float4*>(orow + 4) = make_float4(acc[4], acc[5], acc[6], acc[7]);
    }
}

extern "C" void kernel_launch(void* const* d_in, const int* in_sizes, int n_in,
                              void* d_out, int out_size, void* d_ws, size_t ws_size,
                              hipStream_t stream) {
    const float* q     = (const float*)d_in[0];
    const float* k     = (const float*)d_in[1];
    const float* v     = (const float*)d_in[2];
    const float* edges = (const float*)d_in[3];
    const int*   eidx  = (const int*)d_in[4];
    const float* Wq    = (const float*)d_in[5];
    const float* bq    = (const float*)d_in[6];
    const float* Wk    = (const float*)d_in[7];
    const float* bk    = (const float*)d_in[8];
    const float* Wv    = (const float*)d_in[9];
    const float* bv    = (const float*)d_in[10];
    const float* Wp    = (const float*)d_in[11];
    const float* bp    = (const float*)d_in[12];
    const float* W1    = (const float*)d_in[13];
    const float* b1    = (const float*)d_in[14];
    const float* W2    = (const float*)d_in[15];
    const float* b2    = (const float*)d_in[16];
    float* out = (float*)d_out;

    // workspace layout
    char* ws = (char*)d_ws;
    __half* xq = (__half*)ws;          ws += (size_t)N_NODES * 64 * sizeof(__half);
    __half* xk = (__half*)ws;          ws += (size_t)N_NODES * 64 * sizeof(__half);
    __half* xv = (__half*)ws;          ws += (size_t)N_NODES * 64 * sizeof(__half);
    int* cnt  = (int*)ws;              ws += (size_t)(N_NODES + 64) * sizeof(int);
    int* off  = (int*)ws;              ws += (size_t)(N_NODES + 64) * sizeof(int);
    int* bsum = (int*)ws;              ws += (size_t)64 * sizeof(int);
    float2* ep2e = (float2*)ws;        ws += (size_t)E_EDGES * sizeof(float2);       // 6.4 MB
    ushort* wout = (ushort*)ws;        ws += (size_t)E_EDGES * 8 * sizeof(ushort);   // 12.8 MB
    int* perm    = (int*)ws;           ws += (size_t)E_EDGES * sizeof(int);          // 3.2 MB

    hipMemsetAsync(cnt, 0, (size_t)N_NODES * sizeof(int), stream);

    proj_kernel<<<dim3((N_NODES + 63) / 64), dim3(256), 0, stream>>>(
        q, k, v, Wq, bq, Wk, bk, Wv, bv, xq, xk, xv);

    // edge MLP + histogram (coalesced outputs, edge order)
    edge_weights<<<dim3(E_EDGES / (32 * EW_EPT)), dim3(256), 0, stream>>>(
        eidx, edges, Wp, bp, W1, b1, W2, b2, xq, xk, cnt, ep2e, wout);

    scan_sums<<<dim3(SCAN_NBLK), dim3(256), 0, stream>>>(cnt, bsum);
    scan_bsum<<<dim3(1), dim3(64), 0, stream>>>(bsum);
    scan_final<<<dim3(SCAN_NBLK), dim3(256), 0, stream>>>(cnt, bsum, off);

    perm_scatter<<<dim3(E_EDGES / 256), dim3(256), 0, stream>>>(eidx, cnt, perm);

    node_accum<<<dim3(N_NODES / 16), dim3(256), 0, stream>>>(
        off, perm, ep2e, (const uint4*)wout, xv, out);
}

// Round 10
// 191.949 us; speedup vs baseline: 1.1145x; 1.1145x over previous
//
#include <hip/hip_runtime.h>
#include <hip/hip_fp16.h>

#define N_NODES 50000
#define E_EDGES 800000
#define SCAN_TILE 1024
#define SCAN_NBLK ((N_NODES + SCAN_TILE - 1) / SCAN_TILE)   // 49
#define EW_EPT 5    // edges per quad per wave-iteration: 2500 blocks exact

__device__ __forceinline__ float sgpr_f(float x) {
    return __uint_as_float(__builtin_amdgcn_readfirstlane(__float_as_uint(x)));
}

#if defined(__has_builtin)
#if __has_builtin(__builtin_amdgcn_fdot2)
#define HAS_FDOT2 1
#endif
#endif

typedef _Float16 v2h_t __attribute__((ext_vector_type(2)));

__device__ __forceinline__ float fdot2f(__half2 a, __half2 b, float c) {
#ifdef HAS_FDOT2
    return __builtin_amdgcn_fdot2(*reinterpret_cast<v2h_t*>(&a),
                                  *reinterpret_cast<v2h_t*>(&b), c, false);
#else
    const float2 fa = __half22float2(a);
    const float2 fb = __half22float2(b);
    return fmaf(fa.x, fb.x, fmaf(fa.y, fb.y, c));
#endif
}

// packed relu: v_pk_max_f16 with inline constant 0
__device__ __forceinline__ __half2 relu_h2(__half2 x) {
    union { __half2 h; unsigned u; } a, r;
    a.h = x;
    asm("v_pk_max_f16 %0, %1, 0" : "=v"(r.u) : "v"(a.u));
    return r.h;
}

// quad_perm DPP cross-lane move (VALU pipe, no LDS). 0xB1 = lane^1, 0x4E = lane^2.
template <int CTRL>
__device__ __forceinline__ float dpp_mov_f32(float x) {
    return __int_as_float(__builtin_amdgcn_update_dpp(
        0, __float_as_int(x), CTRL, 0xF, 0xF, true));
}
__device__ __forceinline__ float quad_sum(float x) {
    x += dpp_mov_f32<0xB1>(x);
    x += dpp_mov_f32<0x4E>(x);
    return x;
}
__device__ __forceinline__ float quad_max(float x) {
    x = fmaxf(x, dpp_mov_f32<0xB1>(x));
    x = fmaxf(x, dpp_mov_f32<0x4E>(x));
    return x;
}

// ---------------------------------------------------------------------------
// Projection kernel: xq = q@Wq+bq, xk = k@Wk+bk, xv = v@Wv+bv  (N x 64 each)
// Outputs stored as fp16 to halve downstream gather traffic.
// ---------------------------------------------------------------------------
__global__ __launch_bounds__(256) void proj_kernel(
    const float* __restrict__ qin, const float* __restrict__ kin, const float* __restrict__ vin,
    const float* __restrict__ Wq, const float* __restrict__ bq,
    const float* __restrict__ Wk, const float* __restrict__ bk,
    const float* __restrict__ Wv, const float* __restrict__ bv,
    __half* __restrict__ xq, __half* __restrict__ xk, __half* __restrict__ xv)
{
    __shared__ float Ws[3 * 4096];
    const int tid = threadIdx.x;
    #pragma unroll
    for (int it = 0; it < 16; ++it) {
        const int idx = it * 256 + tid;
        Ws[idx]        = Wq[idx];
        Ws[4096 + idx] = Wk[idx];
        Ws[8192 + idx] = Wv[idx];
    }
    __syncthreads();

    const int cg = tid & 15;
    const int rg = tid >> 4;
    const int c0 = cg * 4;
    const int base = blockIdx.x * 64 + rg * 4;

    const float* ins[3]  = {qin, kin, vin};
    const float* bs[3]   = {bq, bk, bv};
    __half*      outs[3] = {xq, xk, xv};

    int rowi[4];
    #pragma unroll
    for (int rr = 0; rr < 4; ++rr)
        rowi[rr] = (base + rr < N_NODES) ? (base + rr) : (N_NODES - 1);

    #pragma unroll
    for (int m = 0; m < 3; ++m) {
        const float* in = ins[m];
        const float* Wm = &Ws[m * 4096];
        float4 acc[4];
        const float4 b4 = *reinterpret_cast<const float4*>(&bs[m][c0]);
        #pragma unroll
        for (int rr = 0; rr < 4; ++rr) acc[rr] = b4;

        for (int kk = 0; kk < 64; kk += 4) {
            float4 rv[4];
            #pragma unroll
            for (int rr = 0; rr < 4; ++rr)
                rv[rr] = *reinterpret_cast<const float4*>(&in[rowi[rr] * 64 + kk]);
            #pragma unroll
            for (int dk = 0; dk < 4; ++dk) {
                const float4 w4 = *reinterpret_cast<const float4*>(&Wm[(kk + dk) * 64 + c0]);
                #pragma unroll
                for (int rr = 0; rr < 4; ++rr) {
                    const float xs = reinterpret_cast<const float*>(&rv[rr])[dk];
                    acc[rr].x = fmaf(xs, w4.x, acc[rr].x);
                    acc[rr].y = fmaf(xs, w4.y, acc[rr].y);
                    acc[rr].z = fmaf(xs, w4.z, acc[rr].z);
                    acc[rr].w = fmaf(xs, w4.w, acc[rr].w);
                }
            }
        }
        #pragma unroll
        for (int rr = 0; rr < 4; ++rr) {
            if (base + rr < N_NODES) {
                union { __half2 h[2]; uint2 u; } pk;
                pk.h[0] = __floats2half2_rn(acc[rr].x, acc[rr].y);
                pk.h[1] = __floats2half2_rn(acc[rr].z, acc[rr].w);
                *reinterpret_cast<uint2*>(&outs[m][(size_t)(base + rr) * 64 + c0]) = pk.u;
            }
        }
    }
}

// ---------------------------------------------------------------------------
// Hierarchical scan, step A: per-1024-element block sums (49 blocks).
// ---------------------------------------------------------------------------
__global__ __launch_bounds__(256) void scan_sums(
    const int* __restrict__ cnt, int* __restrict__ bsum)
{
    const int tid  = threadIdx.x;
    const int base = blockIdx.x * SCAN_TILE + tid * 4;
    int s = 0;
    if (base + 3 < N_NODES) {
        const int4 t = *reinterpret_cast<const int4*>(&cnt[base]);
        s = t.x + t.y + t.z + t.w;
    } else {
        #pragma unroll
        for (int i = 0; i < 4; ++i)
            if (base + i < N_NODES) s += cnt[base + i];
    }
    #pragma unroll
    for (int d = 1; d < 64; d <<= 1) s += __shfl_xor(s, d);
    __shared__ int ws[4];
    if ((tid & 63) == 0) ws[tid >> 6] = s;
    __syncthreads();
    if (tid == 0) bsum[blockIdx.x] = ws[0] + ws[1] + ws[2] + ws[3];
}

// ---------------------------------------------------------------------------
// Hierarchical scan, step B: exclusive scan of the 49 block sums (one wave).
// ---------------------------------------------------------------------------
__global__ __launch_bounds__(64) void scan_bsum(int* __restrict__ bsum)
{
    const int lane = threadIdx.x;
    const int v = (lane < SCAN_NBLK) ? bsum[lane] : 0;
    int incl = v;
    #pragma unroll
    for (int d = 1; d < 64; d <<= 1) {
        const int t = __shfl_up(incl, d);
        if (lane >= d) incl += t;
    }
    if (lane < SCAN_NBLK) bsum[lane] = incl - v;
}

// ---------------------------------------------------------------------------
// Hierarchical scan, step C: local exclusive scan + block offset.
// Writes off[] and re-purposes cnt[] (in-place) as the scatter cursor.
// ---------------------------------------------------------------------------
__global__ __launch_bounds__(256) void scan_final(
    int* __restrict__ cnt, const int* __restrict__ bsum, int* __restrict__ off)
{
    const int tid  = threadIdx.x;
    const int base = blockIdx.x * SCAN_TILE + tid * 4;

    int v0 = 0, v1 = 0, v2 = 0, v3 = 0;
    if (base + 3 < N_NODES) {
        const int4 t = *reinterpret_cast<const int4*>(&cnt[base]);
        v0 = t.x; v1 = t.y; v2 = t.z; v3 = t.w;
    } else {
        if (base + 0 < N_NODES) v0 = cnt[base + 0];
        if (base + 1 < N_NODES) v1 = cnt[base + 1];
        if (base + 2 < N_NODES) v2 = cnt[base + 2];
        if (base + 3 < N_NODES) v3 = cnt[base + 3];
    }
    const int s = v0 + v1 + v2 + v3;

    int incl = s;
    #pragma unroll
    for (int d = 1; d < 64; d <<= 1) {
        const int t = __shfl_up(incl, d);
        if ((tid & 63) >= d) incl += t;
    }
    __shared__ int wsum[4];
    const int wave = tid >> 6;
    if ((tid & 63) == 63) wsum[wave] = incl;
    __syncthreads();
    int woff = 0;
    #pragma unroll
    for (int w = 0; w < 3; ++w)
        if (w < wave) woff += wsum[w];

    int run = bsum[blockIdx.x] + woff + (incl - s);
    if (base + 0 < N_NODES) { off[base + 0] = run; cnt[base + 0] = run; run += v0; }
    if (base + 1 < N_NODES) { off[base + 1] = run; cnt[base + 1] = run; run += v1; }
    if (base + 2 < N_NODES) { off[base + 2] = run; cnt[base + 2] = run; run += v2; }
    if (base + 3 < N_NODES) { off[base + 3] = run; cnt[base + 3] = run; run += v3; }

    if (blockIdx.x == 0 && tid == 0) off[N_NODES] = E_EDGES;
}

// ---------------------------------------------------------------------------
// Edge-weights kernel, QUAD-per-edge, all exchanges via quad_perm DPP (VALU).
// Lane r (0..3) owns channels 16r..16r+15 (two dwordx4 fp16 loads per row).
// Zero LDS/ds_swizzle ops: p-reduce, h1 all-reduce, softmax max/sum all DPP.
// Lane r computes logits 2r, 2r+1. Coalesced edge-order outputs + histogram.
// ---------------------------------------------------------------------------
__global__ __launch_bounds__(256) void edge_weights(
    const int* __restrict__ eidx, const float* __restrict__ edges,
    const float* __restrict__ Wp, const float* __restrict__ bp,
    const float* __restrict__ W1, const float* __restrict__ b1,
    const float* __restrict__ W2, const float* __restrict__ b2,
    const __half* __restrict__ xq, const __half* __restrict__ xk,
    int* __restrict__ cnt, float2* __restrict__ ep2e, ushort* __restrict__ wout16)
{
    const int tid  = threadIdx.x;
    const int lane = tid & 63;
    const int qid  = lane >> 2;   // quad within wave (edge slot, 16/wave)
    const int r    = lane & 3;    // lane within quad: channels 16r..16r+15
    const int wave = tid >> 6;

    // W1 slice rows 16r..16r+15, packed as half2 over row pairs:
    // W1h[i][j] = { W1[(16r+2i)*8+j], W1[(16r+2i+1)*8+j] }, i=0..7, j=0..7
    __half2 W1h[8][8];
    #pragma unroll
    for (int i = 0; i < 8; ++i) {
        const int row0 = (16 * r + 2 * i) * 8;
        const float4 a0 = *reinterpret_cast<const float4*>(&W1[row0]);
        const float4 a1 = *reinterpret_cast<const float4*>(&W1[row0 + 4]);
        const float4 c0 = *reinterpret_cast<const float4*>(&W1[row0 + 8]);
        const float4 c1 = *reinterpret_cast<const float4*>(&W1[row0 + 12]);
        W1h[i][0] = __floats2half2_rn(a0.x, c0.x);
        W1h[i][1] = __floats2half2_rn(a0.y, c0.y);
        W1h[i][2] = __floats2half2_rn(a0.z, c0.z);
        W1h[i][3] = __floats2half2_rn(a0.w, c0.w);
        W1h[i][4] = __floats2half2_rn(a1.x, c1.x);
        W1h[i][5] = __floats2half2_rn(a1.y, c1.y);
        W1h[i][6] = __floats2half2_rn(a1.z, c1.z);
        W1h[i][7] = __floats2half2_rn(a1.w, c1.w);
    }
    // W2 columns 2r, 2r+1 (this lane's two logits)
    float2 W2c[8];
    #pragma unroll
    for (int j = 0; j < 8; ++j)
        W2c[j] = *reinterpret_cast<const float2*>(&W2[j * 8 + 2 * r]);
    // uniform biases -> SGPRs
    float b1u[8];
    #pragma unroll
    for (int j = 0; j < 8; ++j) b1u[j] = sgpr_f(b1[j]);
    const float b2a = b2[2 * r], b2b = b2[2 * r + 1];
    const float4 wp4 = *reinterpret_cast<const float4*>(&Wp[4 * r]);
    const float bp0 = sgpr_f(bp[0]);

    const int wb = (blockIdx.x * 4 + wave) * (16 * EW_EPT);

    #pragma unroll
    for (int t = 0; t < EW_EPT; ++t) {
        const int e = wb + t * 16 + qid;

        const int2 sd = *reinterpret_cast<const int2*>(&eidx[2 * e]);
        const float4 ev = *reinterpret_cast<const float4*>(&edges[(size_t)e * 16 + 4 * r]);

        const size_t qb = (size_t)sd.x * 64 + 16 * r;
        const size_t kb = (size_t)sd.y * 64 + 16 * r;
        uint4 q0 = *reinterpret_cast<const uint4*>(&xq[qb]);
        uint4 q1 = *reinterpret_cast<const uint4*>(&xq[qb + 8]);
        uint4 k0 = *reinterpret_cast<const uint4*>(&xk[kb]);
        uint4 k1 = *reinterpret_cast<const uint4*>(&xk[kb + 8]);

        // p = edges[e].Wp + bp : dot4 per lane, quad all-reduce via DPP
        float p = fmaf(ev.x, wp4.x, fmaf(ev.y, wp4.y, fmaf(ev.z, wp4.z, ev.w * wp4.w)));
        p = quad_sum(p) + bp0;

        // d = relu(xk - xq + p), packed half2 (8 regs = 16 channels)
        const __half2 p2 = __float2half2_rn(p);
        const __half2* qh0 = reinterpret_cast<const __half2*>(&q0);
        const __half2* qh1 = reinterpret_cast<const __half2*>(&q1);
        const __half2* kh0 = reinterpret_cast<const __half2*>(&k0);
        const __half2* kh1 = reinterpret_cast<const __half2*>(&k1);
        __half2 dh[8];
        #pragma unroll
        for (int i = 0; i < 4; ++i) {
            dh[i]     = relu_h2(__hadd2(__hsub2(kh0[i], qh0[i]), p2));
            dh[i + 4] = relu_h2(__hadd2(__hsub2(kh1[i], qh1[i]), p2));
        }

        // h1 partials: 64 dot2 per lane
        float part[8];
        #pragma unroll
        for (int j = 0; j < 8; ++j) part[j] = 0.f;
        #pragma unroll
        for (int i = 0; i < 8; ++i) {
            #pragma unroll
            for (int j = 0; j < 8; ++j)
                part[j] = fdot2f(dh[i], W1h[i][j], part[j]);
        }
        // quad all-reduce (DPP): every lane gets full h1
        #pragma unroll
        for (int j = 0; j < 8; ++j) part[j] = quad_sum(part[j]);

        // two logits per lane
        float g[8];
        #pragma unroll
        for (int j = 0; j < 8; ++j) g[j] = fmaxf(part[j] + b1u[j], 0.f);
        float h2a = b2a, h2b = b2b;
        #pragma unroll
        for (int j = 0; j < 8; ++j) {
            h2a = fmaf(g[j], W2c[j].x, h2a);
            h2b = fmaf(g[j], W2c[j].y, h2b);
        }

        // softmax over 8 logits (2 per lane, DPP reduces)
        const float m  = quad_max(fmaxf(h2a, h2b));
        const float ea = __expf(h2a - m);
        const float eb = __expf(h2b - m);
        const float s  = quad_sum(ea + eb);
        const float inv = 1.f / s;

        // coalesced edge-order outputs: lane r writes weight slots 2r, 2r+1
        union { __half2 h; unsigned u; } w2;
        w2.h = __floats2half2_rn(ea * inv, eb * inv);
        *reinterpret_cast<unsigned*>(&wout16[(size_t)e * 8 + 2 * r]) = w2.u;
        if (r == 0) ep2e[e] = make_float2(p, __int_as_float(sd.y));
        if (r == 1) atomicAdd(&cnt[sd.x], 1);
    }
}

// ---------------------------------------------------------------------------
// Scatter: move precomputed {p,dst} + 16B weight record into CSR order.
// ---------------------------------------------------------------------------
__global__ __launch_bounds__(256) void scatter_kernel(
    const int* __restrict__ eidx, const float2* __restrict__ ep2e,
    const uint4* __restrict__ woute,
    int* __restrict__ cursor, float2* __restrict__ ep2, uint4* __restrict__ wcsr)
{
    const int e = blockIdx.x * 256 + threadIdx.x;
    const int src = eidx[2 * e];
    const float2 ep = ep2e[e];
    const uint4 w8 = woute[e];

    const int pos = atomicAdd(&cursor[src], 1);
    ep2[pos]  = ep;
    wcsr[pos] = w8;
}

// ---------------------------------------------------------------------------
// Node accumulation: 16 lanes per node (2 sub-octets split the edge list,
// stride 2). Lane r owns channels 8r..8r+7. Pure gather-FMA over the
// CSR-ordered records (linear streams) + xv row gather.
// ---------------------------------------------------------------------------
__global__ __launch_bounds__(256) void node_accum(
    const int* __restrict__ off, const float2* __restrict__ ep2,
    const uint4* __restrict__ wcsr, const __half* __restrict__ xv,
    float* __restrict__ out)
{
    const int tid  = threadIdx.x;
    const int lane = tid & 63;
    const int grp  = lane >> 4;        // 4 node-groups per wave
    const int sub  = (lane >> 3) & 1;  // sub-octet within group
    const int r    = lane & 7;         // channel block
    const int wave = tid >> 6;

    const int node = blockIdx.x * 16 + wave * 4 + grp;   // always < 50000

    const int beg = off[node];
    const int end = off[node + 1];

    float acc[8];
    #pragma unroll
    for (int i = 0; i < 8; ++i) acc[i] = 0.f;

    int j = beg + sub;
    float2 ep;
    uint4  w8;
    if (j < end) { ep = ep2[j]; w8 = wcsr[j]; }

    for (; j < end; j += 2) {
        const float p   = ep.x;
        const int   dst = __float_as_int(ep.y);

        union { uint4 u; __half2 h[4]; } v4, wz;
        v4.u = *reinterpret_cast<const uint4*>(&xv[(size_t)dst * 64 + 8 * r]);
        wz.u = w8;

        // prefetch next record (linear)
        if (j + 2 < end) { ep = ep2[j + 2]; w8 = wcsr[j + 2]; }

        #pragma unroll
        for (int i = 0; i < 4; ++i) {
            const float2 fv = __half22float2(v4.h[i]);
            const float2 fw = __half22float2(wz.h[i]);
            acc[2 * i]     = fmaf(fv.x + p, fw.x, acc[2 * i]);
            acc[2 * i + 1] = fmaf(fv.y + p, fw.y, acc[2 * i + 1]);
        }
    }

    // merge the two sub-octets
    #pragma unroll
    for (int i = 0; i < 8; ++i)
        acc[i] += __shfl_xor(acc[i], 8);

    if (sub == 0) {
        float* orow = &out[(size_t)node * 64 + 8 * r];
        *reinterpret_cast<float4*>(orow)     = make_float4(acc[0], acc[1], acc[2], acc[3]);
        *reinterpret_cast<float4*>(orow + 4) = make_float4(acc[4], acc[5], acc[6], acc[7]);
    }
}

extern "C" void kernel_launch(void* const* d_in, const int* in_sizes, int n_in,
                              void* d_out, int out_size, void* d_ws, size_t ws_size,
                              hipStream_t stream) {
    const float* q     = (const float*)d_in[0];
    const float* k     = (const float*)d_in[1];
    const float* v     = (const float*)d_in[2];
    const float* edges = (const float*)d_in[3];
    const int*   eidx  = (const int*)d_in[4];
    const float* Wq    = (const float*)d_in[5];
    const float* bq    = (const float*)d_in[6];
    const float* Wk    = (const float*)d_in[7];
    const float* bk    = (const float*)d_in[8];
    const float* Wv    = (const float*)d_in[9];
    const float* bv    = (const float*)d_in[10];
    const float* Wp    = (const float*)d_in[11];
    const float* bp    = (const float*)d_in[12];
    const float* W1    = (const float*)d_in[13];
    const float* b1    = (const float*)d_in[14];
    const float* W2    = (const float*)d_in[15];
    const float* b2    = (const float*)d_in[16];
    float* out = (float*)d_out;

    // workspace layout
    char* ws = (char*)d_ws;
    __half* xq = (__half*)ws;          ws += (size_t)N_NODES * 64 * sizeof(__half);
    __half* xk = (__half*)ws;          ws += (size_t)N_NODES * 64 * sizeof(__half);
    __half* xv = (__half*)ws;          ws += (size_t)N_NODES * 64 * sizeof(__half);
    int* cnt  = (int*)ws;              ws += (size_t)(N_NODES + 64) * sizeof(int);
    int* off  = (int*)ws;              ws += (size_t)(N_NODES + 64) * sizeof(int);
    int* bsum = (int*)ws;              ws += (size_t)64 * sizeof(int);
    float2* ep2e = (float2*)ws;        ws += (size_t)E_EDGES * sizeof(float2);       // 6.4 MB
    ushort* wout = (ushort*)ws;        ws += (size_t)E_EDGES * 8 * sizeof(ushort);   // 12.8 MB
    float2* ep2  = (float2*)ws;        ws += (size_t)E_EDGES * sizeof(float2);       // 6.4 MB
    uint4*  wcsr = (uint4*)ws;         ws += (size_t)E_EDGES * sizeof(uint4);        // 12.8 MB

    hipMemsetAsync(cnt, 0, (size_t)N_NODES * sizeof(int), stream);

    proj_kernel<<<dim3((N_NODES + 63) / 64), dim3(256), 0, stream>>>(
        q, k, v, Wq, bq, Wk, bk, Wv, bv, xq, xk, xv);

    // edge MLP + histogram (coalesced outputs, edge order), quad-DPP version
    edge_weights<<<dim3(E_EDGES / (64 * EW_EPT)), dim3(256), 0, stream>>>(
        eidx, edges, Wp, bp, W1, b1, W2, b2, xq, xk, cnt, ep2e, wout);

    scan_sums<<<dim3(SCAN_NBLK), dim3(256), 0, stream>>>(cnt, bsum);
    scan_bsum<<<dim3(1), dim3(64), 0, stream>>>(bsum);
    scan_final<<<dim3(SCAN_NBLK), dim3(256), 0, stream>>>(cnt, bsum, off);

    scatter_kernel<<<dim3(E_EDGES / 256), dim3(256), 0, stream>>>(
        eidx, ep2e, (const uint4*)wout, cnt, ep2, wcsr);

    node_accum<<<dim3(N_NODES / 16), dim3(256), 0, stream>>>(
        off, ep2, wcsr, xv, out);
}

// Round 11
// 187.402 us; speedup vs baseline: 1.1416x; 1.0243x over previous
//
#include <hip/hip_runtime.h>
#include <hip/hip_fp16.h>

#define N_NODES 50000
#define E_EDGES 800000
#define SCAN_TILE 1024
#define SCAN_NBLK ((N_NODES + SCAN_TILE - 1) / SCAN_TILE)   // 49
#define EW_EPT 4    // edges per octet per wave-iteration

__device__ __forceinline__ float sgpr_f(float x) {
    return __uint_as_float(__builtin_amdgcn_readfirstlane(__float_as_uint(x)));
}

#if defined(__has_builtin)
#if __has_builtin(__builtin_amdgcn_fdot2)
#define HAS_FDOT2 1
#endif
#endif

typedef _Float16 v2h_t __attribute__((ext_vector_type(2)));

__device__ __forceinline__ float fdot2f(__half2 a, __half2 b, float c) {
#ifdef HAS_FDOT2
    return __builtin_amdgcn_fdot2(*reinterpret_cast<v2h_t*>(&a),
                                  *reinterpret_cast<v2h_t*>(&b), c, false);
#else
    const float2 fa = __half22float2(a);
    const float2 fb = __half22float2(b);
    return fmaf(fa.x, fb.x, fmaf(fa.y, fb.y, c));
#endif
}

// packed relu: v_pk_max_f16 with inline constant 0
__device__ __forceinline__ __half2 relu_h2(__half2 x) {
    union { __half2 h; unsigned u; } a, r;
    a.h = x;
    asm("v_pk_max_f16 %0, %1, 0" : "=v"(r.u) : "v"(a.u));
    return r.h;
}

// DPP cross-lane moves (VALU pipe, no LDS).
// 0xB1 = quad_perm [1,0,3,2] (lane^1), 0x4E = quad_perm [2,3,0,1] (lane^2),
// 0x141 = ROW_HALF_MIRROR (lane i <-> 7-i within each aligned 8-lane group).
template <int CTRL>
__device__ __forceinline__ float dpp_mov_f32(float x) {
    return __int_as_float(__builtin_amdgcn_update_dpp(
        0, __float_as_int(x), CTRL, 0xF, 0xF, true));
}
// full 8-lane (octet) reduction: quad xor1 + quad xor2 + half-mirror
__device__ __forceinline__ float oct_sum(float x) {
    x += dpp_mov_f32<0xB1>(x);
    x += dpp_mov_f32<0x4E>(x);
    x += dpp_mov_f32<0x141>(x);
    return x;
}
__device__ __forceinline__ float oct_max(float x) {
    x = fmaxf(x, dpp_mov_f32<0xB1>(x));
    x = fmaxf(x, dpp_mov_f32<0x4E>(x));
    x = fmaxf(x, dpp_mov_f32<0x141>(x));
    return x;
}

// ---------------------------------------------------------------------------
// Projection kernel: xq = q@Wq+bq, xk = k@Wk+bk, xv = v@Wv+bv  (N x 64 each)
// Outputs stored as fp16 to halve downstream gather traffic.
// ---------------------------------------------------------------------------
__global__ __launch_bounds__(256) void proj_kernel(
    const float* __restrict__ qin, const float* __restrict__ kin, const float* __restrict__ vin,
    const float* __restrict__ Wq, const float* __restrict__ bq,
    const float* __restrict__ Wk, const float* __restrict__ bk,
    const float* __restrict__ Wv, const float* __restrict__ bv,
    __half* __restrict__ xq, __half* __restrict__ xk, __half* __restrict__ xv)
{
    __shared__ float Ws[3 * 4096];
    const int tid = threadIdx.x;
    #pragma unroll
    for (int it = 0; it < 16; ++it) {
        const int idx = it * 256 + tid;
        Ws[idx]        = Wq[idx];
        Ws[4096 + idx] = Wk[idx];
        Ws[8192 + idx] = Wv[idx];
    }
    __syncthreads();

    const int cg = tid & 15;
    const int rg = tid >> 4;
    const int c0 = cg * 4;
    const int base = blockIdx.x * 64 + rg * 4;

    const float* ins[3]  = {qin, kin, vin};
    const float* bs[3]   = {bq, bk, bv};
    __half*      outs[3] = {xq, xk, xv};

    int rowi[4];
    #pragma unroll
    for (int rr = 0; rr < 4; ++rr)
        rowi[rr] = (base + rr < N_NODES) ? (base + rr) : (N_NODES - 1);

    #pragma unroll
    for (int m = 0; m < 3; ++m) {
        const float* in = ins[m];
        const float* Wm = &Ws[m * 4096];
        float4 acc[4];
        const float4 b4 = *reinterpret_cast<const float4*>(&bs[m][c0]);
        #pragma unroll
        for (int rr = 0; rr < 4; ++rr) acc[rr] = b4;

        for (int kk = 0; kk < 64; kk += 4) {
            float4 rv[4];
            #pragma unroll
            for (int rr = 0; rr < 4; ++rr)
                rv[rr] = *reinterpret_cast<const float4*>(&in[rowi[rr] * 64 + kk]);
            #pragma unroll
            for (int dk = 0; dk < 4; ++dk) {
                const float4 w4 = *reinterpret_cast<const float4*>(&Wm[(kk + dk) * 64 + c0]);
                #pragma unroll
                for (int rr = 0; rr < 4; ++rr) {
                    const float xs = reinterpret_cast<const float*>(&rv[rr])[dk];
                    acc[rr].x = fmaf(xs, w4.x, acc[rr].x);
                    acc[rr].y = fmaf(xs, w4.y, acc[rr].y);
                    acc[rr].z = fmaf(xs, w4.z, acc[rr].z);
                    acc[rr].w = fmaf(xs, w4.w, acc[rr].w);
                }
            }
        }
        #pragma unroll
        for (int rr = 0; rr < 4; ++rr) {
            if (base + rr < N_NODES) {
                union { __half2 h[2]; uint2 u; } pk;
                pk.h[0] = __floats2half2_rn(acc[rr].x, acc[rr].y);
                pk.h[1] = __floats2half2_rn(acc[rr].z, acc[rr].w);
                *reinterpret_cast<uint2*>(&outs[m][(size_t)(base + rr) * 64 + c0]) = pk.u;
            }
        }
    }
}

// ---------------------------------------------------------------------------
// Hierarchical scan, step A: per-1024-element block sums (49 blocks).
// ---------------------------------------------------------------------------
__global__ __launch_bounds__(256) void scan_sums(
    const int* __restrict__ cnt, int* __restrict__ bsum)
{
    const int tid  = threadIdx.x;
    const int base = blockIdx.x * SCAN_TILE + tid * 4;
    int s = 0;
    if (base + 3 < N_NODES) {
        const int4 t = *reinterpret_cast<const int4*>(&cnt[base]);
        s = t.x + t.y + t.z + t.w;
    } else {
        #pragma unroll
        for (int i = 0; i < 4; ++i)
            if (base + i < N_NODES) s += cnt[base + i];
    }
    #pragma unroll
    for (int d = 1; d < 64; d <<= 1) s += __shfl_xor(s, d);
    __shared__ int ws[4];
    if ((tid & 63) == 0) ws[tid >> 6] = s;
    __syncthreads();
    if (tid == 0) bsum[blockIdx.x] = ws[0] + ws[1] + ws[2] + ws[3];
}

// ---------------------------------------------------------------------------
// Hierarchical scan, step B: exclusive scan of the 49 block sums (one wave).
// ---------------------------------------------------------------------------
__global__ __launch_bounds__(64) void scan_bsum(int* __restrict__ bsum)
{
    const int lane = threadIdx.x;
    const int v = (lane < SCAN_NBLK) ? bsum[lane] : 0;
    int incl = v;
    #pragma unroll
    for (int d = 1; d < 64; d <<= 1) {
        const int t = __shfl_up(incl, d);
        if (lane >= d) incl += t;
    }
    if (lane < SCAN_NBLK) bsum[lane] = incl - v;
}

// ---------------------------------------------------------------------------
// Hierarchical scan, step C: local exclusive scan + block offset.
// Writes off[] and re-purposes cnt[] (in-place) as the scatter cursor.
// ---------------------------------------------------------------------------
__global__ __launch_bounds__(256) void scan_final(
    int* __restrict__ cnt, const int* __restrict__ bsum, int* __restrict__ off)
{
    const int tid  = threadIdx.x;
    const int base = blockIdx.x * SCAN_TILE + tid * 4;

    int v0 = 0, v1 = 0, v2 = 0, v3 = 0;
    if (base + 3 < N_NODES) {
        const int4 t = *reinterpret_cast<const int4*>(&cnt[base]);
        v0 = t.x; v1 = t.y; v2 = t.z; v3 = t.w;
    } else {
        if (base + 0 < N_NODES) v0 = cnt[base + 0];
        if (base + 1 < N_NODES) v1 = cnt[base + 1];
        if (base + 2 < N_NODES) v2 = cnt[base + 2];
        if (base + 3 < N_NODES) v3 = cnt[base + 3];
    }
    const int s = v0 + v1 + v2 + v3;

    int incl = s;
    #pragma unroll
    for (int d = 1; d < 64; d <<= 1) {
        const int t = __shfl_up(incl, d);
        if ((tid & 63) >= d) incl += t;
    }
    __shared__ int wsum[4];
    const int wave = tid >> 6;
    if ((tid & 63) == 63) wsum[wave] = incl;
    __syncthreads();
    int woff = 0;
    #pragma unroll
    for (int w = 0; w < 3; ++w)
        if (w < wave) woff += wsum[w];

    int run = bsum[blockIdx.x] + woff + (incl - s);
    if (base + 0 < N_NODES) { off[base + 0] = run; cnt[base + 0] = run; run += v0; }
    if (base + 1 < N_NODES) { off[base + 1] = run; cnt[base + 1] = run; run += v1; }
    if (base + 2 < N_NODES) { off[base + 2] = run; cnt[base + 2] = run; run += v2; }
    if (base + 3 < N_NODES) { off[base + 3] = run; cnt[base + 3] = run; run += v3; }

    if (blockIdx.x == 0 && tid == 0) off[N_NODES] = E_EDGES;
}

// ---------------------------------------------------------------------------
// Edge-weights kernel: octet-per-edge, ALL cross-lane ops via DPP (VALU).
// Lane r (0..7) owns channels 8r..8r+7 (one dwordx4 fp16 load per node row).
// W1 slice = 32 VGPRs (half2-packed). Coalesced edge-order outputs.
// ---------------------------------------------------------------------------
__global__ __launch_bounds__(256) void edge_weights(
    const int* __restrict__ eidx, const float* __restrict__ edges,
    const float* __restrict__ Wp, const float* __restrict__ bp,
    const float* __restrict__ W1, const float* __restrict__ b1,
    const float* __restrict__ W2, const float* __restrict__ b2,
    const __half* __restrict__ xq, const __half* __restrict__ xk,
    int* __restrict__ cnt, float2* __restrict__ ep2e, ushort* __restrict__ wout16)
{
    const int tid  = threadIdx.x;
    const int lane = tid & 63;
    const int o    = lane >> 3;   // octet within wave (edge slot)
    const int r    = lane & 7;    // lane within octet: channels 8r..8r+7
    const int wave = tid >> 6;

    // W1 slice rows 8r..8r+7 packed as half2 over row pairs (32 VGPRs):
    // W1h[i][jj] = { W1[(8r+2i)*8+jj], W1[(8r+2i+1)*8+jj] }
    __half2 W1h[4][8];
    #pragma unroll
    for (int i = 0; i < 4; ++i) {
        const float4 a0 = *reinterpret_cast<const float4*>(&W1[(8 * r + 2 * i) * 8]);
        const float4 a1 = *reinterpret_cast<const float4*>(&W1[(8 * r + 2 * i) * 8 + 4]);
        const float4 c0 = *reinterpret_cast<const float4*>(&W1[(8 * r + 2 * i + 1) * 8]);
        const float4 c1 = *reinterpret_cast<const float4*>(&W1[(8 * r + 2 * i + 1) * 8 + 4]);
        W1h[i][0] = __floats2half2_rn(a0.x, c0.x);
        W1h[i][1] = __floats2half2_rn(a0.y, c0.y);
        W1h[i][2] = __floats2half2_rn(a0.z, c0.z);
        W1h[i][3] = __floats2half2_rn(a0.w, c0.w);
        W1h[i][4] = __floats2half2_rn(a1.x, c1.x);
        W1h[i][5] = __floats2half2_rn(a1.y, c1.y);
        W1h[i][6] = __floats2half2_rn(a1.z, c1.z);
        W1h[i][7] = __floats2half2_rn(a1.w, c1.w);
    }
    // W2 column r (per-lane, distributed logit)
    float W2col[8];
    #pragma unroll
    for (int jj = 0; jj < 8; ++jj) W2col[jj] = W2[jj * 8 + r];
    // uniform biases -> SGPRs
    float b1u[8];
    #pragma unroll
    for (int j = 0; j < 8; ++j) b1u[j] = sgpr_f(b1[j]);
    const float b2r = b2[r];
    const float wpA = Wp[2 * r], wpB = Wp[2 * r + 1];
    const float bp0 = sgpr_f(bp[0]);

    const int wb = (blockIdx.x * 4 + wave) * (8 * EW_EPT);

    #pragma unroll
    for (int t = 0; t < EW_EPT; ++t) {
        const int e = wb + t * 8 + o;

        const int2 sd = *reinterpret_cast<const int2*>(&eidx[2 * e]);
        const float2 e2 = *reinterpret_cast<const float2*>(&edges[(size_t)e * 16 + 2 * r]);

        uint4 q4u = *reinterpret_cast<const uint4*>(&xq[(size_t)sd.x * 64 + 8 * r]);
        uint4 k4u = *reinterpret_cast<const uint4*>(&xk[(size_t)sd.y * 64 + 8 * r]);

        // p = edges[e].Wp + bp (16-dot over the octet, DPP reduce)
        float p = fmaf(e2.x, wpA, e2.y * wpB);
        p = oct_sum(p) + bp0;

        // relu(xk - xq + p) in packed half2, then dot2 into f32 partials
        const __half2 p2 = __float2half2_rn(p);
        const __half2* qh = reinterpret_cast<const __half2*>(&q4u);
        const __half2* kh = reinterpret_cast<const __half2*>(&k4u);

        float part[8];
        #pragma unroll
        for (int jj = 0; jj < 8; ++jj) part[jj] = 0.f;
        #pragma unroll
        for (int i = 0; i < 4; ++i) {
            const __half2 d = relu_h2(__hadd2(__hsub2(kh[i], qh[i]), p2));
            #pragma unroll
            for (int jj = 0; jj < 8; ++jj)
                part[jj] = fdot2f(d, W1h[i][jj], part[jj]);
        }
        // octet all-reduce via DPP: every lane gets the full h1 vector
        #pragma unroll
        for (int jj = 0; jj < 8; ++jj) part[jj] = oct_sum(part[jj]);

        // distributed logit: lane r computes h2[r] only
        float h2 = b2r;
        #pragma unroll
        for (int jj = 0; jj < 8; ++jj) {
            const float h1 = fmaxf(part[jj] + b1u[jj], 0.f);
            h2 = fmaf(h1, W2col[jj], h2);
        }

        // octet softmax, DPP reduces
        const float mx = oct_max(h2);
        const float ex = __expf(h2 - mx);
        const float s  = oct_sum(ex);
        const float w  = ex / s;

        // coalesced edge-order outputs
        wout16[(size_t)e * 8 + r] = __half_as_ushort(__float2half_rn(w));
        if (r == 0) ep2e[e] = make_float2(p, __int_as_float(sd.y));
        if (r == 1) atomicAdd(&cnt[sd.x], 1);
    }
}

// ---------------------------------------------------------------------------
// Scatter: move precomputed {p,dst} + 16B weight record into CSR order.
// ---------------------------------------------------------------------------
__global__ __launch_bounds__(256) void scatter_kernel(
    const int* __restrict__ eidx, const float2* __restrict__ ep2e,
    const uint4* __restrict__ woute,
    int* __restrict__ cursor, float2* __restrict__ ep2, uint4* __restrict__ wcsr)
{
    const int e = blockIdx.x * 256 + threadIdx.x;
    const int src = eidx[2 * e];
    const float2 ep = ep2e[e];
    const uint4 w8 = woute[e];

    const int pos = atomicAdd(&cursor[src], 1);
    ep2[pos]  = ep;
    wcsr[pos] = w8;
}

// ---------------------------------------------------------------------------
// Node accumulation: 16 lanes per node (2 sub-octets split the edge list,
// stride 2). Lane r owns channels 8r..8r+7. Pure gather-FMA over the
// CSR-ordered records (linear streams) + xv row gather.
// ---------------------------------------------------------------------------
__global__ __launch_bounds__(256) void node_accum(
    const int* __restrict__ off, const float2* __restrict__ ep2,
    const uint4* __restrict__ wcsr, const __half* __restrict__ xv,
    float* __restrict__ out)
{
    const int tid  = threadIdx.x;
    const int lane = tid & 63;
    const int grp  = lane >> 4;        // 4 node-groups per wave
    const int sub  = (lane >> 3) & 1;  // sub-octet within group
    const int r    = lane & 7;         // channel block
    const int wave = tid >> 6;

    const int node = blockIdx.x * 16 + wave * 4 + grp;   // always < 50000

    const int beg = off[node];
    const int end = off[node + 1];

    float acc[8];
    #pragma unroll
    for (int i = 0; i < 8; ++i) acc[i] = 0.f;

    int j = beg + sub;
    float2 ep;
    uint4  w8;
    if (j < end) { ep = ep2[j]; w8 = wcsr[j]; }

    for (; j < end; j += 2) {
        const float p   = ep.x;
        const int   dst = __float_as_int(ep.y);

        union { uint4 u; __half2 h[4]; } v4, wz;
        v4.u = *reinterpret_cast<const uint4*>(&xv[(size_t)dst * 64 + 8 * r]);
        wz.u = w8;

        // prefetch next record (linear)
        if (j + 2 < end) { ep = ep2[j + 2]; w8 = wcsr[j + 2]; }

        #pragma unroll
        for (int i = 0; i < 4; ++i) {
            const float2 fv = __half22float2(v4.h[i]);
            const float2 fw = __half22float2(wz.h[i]);
            acc[2 * i]     = fmaf(fv.x + p, fw.x, acc[2 * i]);
            acc[2 * i + 1] = fmaf(fv.y + p, fw.y, acc[2 * i + 1]);
        }
    }

    // merge the two sub-octets
    #pragma unroll
    for (int i = 0; i < 8; ++i)
        acc[i] += __shfl_xor(acc[i], 8);

    if (sub == 0) {
        float* orow = &out[(size_t)node * 64 + 8 * r];
        *reinterpret_cast<float4*>(orow)     = make_float4(acc[0], acc[1], acc[2], acc[3]);
        *reinterpret_cast<float4*>(orow + 4) = make_float4(acc[4], acc[5], acc[6], acc[7]);
    }
}

extern "C" void kernel_launch(void* const* d_in, const int* in_sizes, int n_in,
                              void* d_out, int out_size, void* d_ws, size_t ws_size,
                              hipStream_t stream) {
    const float* q     = (const float*)d_in[0];
    const float* k     = (const float*)d_in[1];
    const float* v     = (const float*)d_in[2];
    const float* edges = (const float*)d_in[3];
    const int*   eidx  = (const int*)d_in[4];
    const float* Wq    = (const float*)d_in[5];
    const float* bq    = (const float*)d_in[6];
    const float* Wk    = (const float*)d_in[7];
    const float* bk    = (const float*)d_in[8];
    const float* Wv    = (const float*)d_in[9];
    const float* bv    = (const float*)d_in[10];
    const float* Wp    = (const float*)d_in[11];
    const float* bp    = (const float*)d_in[12];
    const float* W1    = (const float*)d_in[13];
    const float* b1    = (const float*)d_in[14];
    const float* W2    = (const float*)d_in[15];
    const float* b2    = (const float*)d_in[16];
    float* out = (float*)d_out;

    // workspace layout
    char* ws = (char*)d_ws;
    __half* xq = (__half*)ws;          ws += (size_t)N_NODES * 64 * sizeof(__half);
    __half* xk = (__half*)ws;          ws += (size_t)N_NODES * 64 * sizeof(__half);
    __half* xv = (__half*)ws;          ws += (size_t)N_NODES * 64 * sizeof(__half);
    int* cnt  = (int*)ws;              ws += (size_t)(N_NODES + 64) * sizeof(int);
    int* off  = (int*)ws;              ws += (size_t)(N_NODES + 64) * sizeof(int);
    int* bsum = (int*)ws;              ws += (size_t)64 * sizeof(int);
    float2* ep2e = (float2*)ws;        ws += (size_t)E_EDGES * sizeof(float2);       // 6.4 MB
    ushort* wout = (ushort*)ws;        ws += (size_t)E_EDGES * 8 * sizeof(ushort);   // 12.8 MB
    float2* ep2  = (float2*)ws;        ws += (size_t)E_EDGES * sizeof(float2);       // 6.4 MB
    uint4*  wcsr = (uint4*)ws;         ws += (size_t)E_EDGES * sizeof(uint4);        // 12.8 MB

    hipMemsetAsync(cnt, 0, (size_t)N_NODES * sizeof(int), stream);

    proj_kernel<<<dim3((N_NODES + 63) / 64), dim3(256), 0, stream>>>(
        q, k, v, Wq, bq, Wk, bk, Wv, bv, xq, xk, xv);

    // edge MLP + histogram (coalesced outputs, edge order), octet-DPP version
    edge_weights<<<dim3(E_EDGES / (32 * EW_EPT)), dim3(256), 0, stream>>>(
        eidx, edges, Wp, bp, W1, b1, W2, b2, xq, xk, cnt, ep2e, wout);

    scan_sums<<<dim3(SCAN_NBLK), dim3(256), 0, stream>>>(cnt, bsum);
    scan_bsum<<<dim3(1), dim3(64), 0, stream>>>(bsum);
    scan_final<<<dim3(SCAN_NBLK), dim3(256), 0, stream>>>(cnt, bsum, off);

    scatter_kernel<<<dim3(E_EDGES / 256), dim3(256), 0, stream>>>(
        eidx, ep2e, (const uint4*)wout, cnt, ep2, wcsr);

    node_accum<<<dim3(N_NODES / 16), dim3(256), 0, stream>>>(
        off, ep2, wcsr, xv, out);
}